// Round 1
// 114.596 us; speedup vs baseline: 1.1068x; 1.1068x over previous
//
#include <hip/hip_runtime.h>

typedef _Float16 h2 __attribute__((ext_vector_type(2)));
typedef _Float16 f16x8 __attribute__((ext_vector_type(8)));
typedef float f32x4 __attribute__((ext_vector_type(4)));
typedef unsigned int uint32;

#define BB 8
#define NN 256
#define FF 59
#define CC 128
#define EPSV 1e-5f

// ws layout (dword offsets)
#define WS_V     0
#define WS_ASRC  (WS_V + BB*NN*CC)
#define WS_ADST  (WS_ASRC + BB*NN*CC)
#define WS_PWT   (WS_ADST + BB*NN*CC)
#define WS_T1    (WS_PWT + 6*CC)
#define WS_T2    (WS_T1 + CC)
#define WS_WTB   (WS_T2 + CC)   // 32*64 uint4 = 8192 dwords: attn_w folded+packed in MFMA B-fragment order

// blocks 0..767: projections, 8 n-rows each (type = blk>>8: 0=v, 1=a_src, 2=a_dst)
// block  768   : fold BN into pos_w (-> pwt, T1) and attn_w (-> wtB f16 B-fragments, T2)
__global__ __launch_bounds__(256) void prep_kernel(
    const float* __restrict__ x, const float* __restrict__ W_lin,
    const float* __restrict__ W_src, const float* __restrict__ W_dst,
    const float* __restrict__ pos_w, const float* __restrict__ pos_b,
    const float* __restrict__ pos_g, const float* __restrict__ pos_bb,
    const float* __restrict__ pos_m, const float* __restrict__ pos_v,
    const float* __restrict__ attn_w, const float* __restrict__ attn_b,
    const float* __restrict__ attn_g, const float* __restrict__ attn_bb,
    const float* __restrict__ attn_m, const float* __restrict__ attn_v,
    float* __restrict__ ws)
{
    int blk = blockIdx.x;
    int tid = threadIdx.x;
    if (blk < 768) {
        int type = blk >> 8;
        int g    = blk & 255;
        int b    = g >> 5;
        int n0   = (g & 31) * 8;
        const float* W = (type == 0) ? W_lin : (type == 1) ? W_src : W_dst;
        float* outp = ws + ((type == 0) ? WS_V : (type == 1) ? WS_ASRC : WS_ADST);
        __shared__ float Wl[CC * 60];   // rows padded 59->60 for aligned b128
        __shared__ float xs[8 * 60];
        for (int idx = tid; idx < CC * 60; idx += 256) {
            int r = idx / 60, f = idx - r * 60;
            Wl[idx] = (f < FF) ? W[r * FF + f] : 0.f;
        }
        const float* xrow = x + (size_t)(b * NN + n0) * FF;
        for (int idx = tid; idx < 8 * 60; idx += 256) {
            int r = idx / 60, f = idx - r * 60;
            xs[idx] = (f < FF) ? xrow[r * FF + f] : 0.f;
        }
        __syncthreads();
        int c = tid & 127, h = tid >> 7;
        float acc[4];
#pragma unroll
        for (int q = 0; q < 4; ++q) acc[q] = 0.f;
#pragma unroll 3
        for (int f4 = 0; f4 < 15; ++f4) {
            float4 wq = *(const float4*)&Wl[c * 60 + f4 * 4];
#pragma unroll
            for (int q = 0; q < 4; ++q) {
                float4 xq = *(const float4*)&xs[(h * 4 + q) * 60 + f4 * 4];
                acc[q] = fmaf(wq.x, xq.x, acc[q]);
                acc[q] = fmaf(wq.y, xq.y, acc[q]);
                acc[q] = fmaf(wq.z, xq.z, acc[q]);
                acc[q] = fmaf(wq.w, xq.w, acc[q]);
            }
        }
#pragma unroll
        for (int q = 0; q < 4; ++q) {
            int n = n0 + h * 4 + q;
            outp[(b * NN + n) * CC + c] = acc[q];
        }
    } else {
        __shared__ float S2s[CC];
        if (tid < CC) {
            int c = tid;
            float S1 = rsqrtf(pos_v[c] + EPSV) * pos_g[c];
            ws[WS_T1 + c] = (pos_b[c] - pos_m[c]) * S1 + pos_bb[c];
#pragma unroll
            for (int k = 0; k < 6; ++k) ws[WS_PWT + k * CC + c] = pos_w[c * 6 + k] * S1;
            float S2 = rsqrtf(attn_v[c] + EPSV) * attn_g[c];
            S2s[c] = S2;
            ws[WS_T2 + c] = (attn_b[c] - attn_m[c]) * S2 + attn_bb[c];
        }
        __syncthreads();
        // Build wtB: f16 B-fragments for mfma_f32_16x16x32_f16.
        // Fragment entry (ts = t*4+s, lane l, elem e):
        //   value = attn_w[d][c]*S2[d],  d = t*16 + (l&15),  c = s*32 + (l>>4)*8 + e
        uint4* wtbp = (uint4*)(ws + WS_WTB);
        for (int idx = tid; idx < 32 * 64; idx += 256) {
            int l = idx & 63, ts = idx >> 6;
            int t = ts >> 2, s = ts & 3;
            int d  = t * 16 + (l & 15);
            int c0 = s * 32 + ((l >> 4) << 3);
            float S2 = S2s[d];
            float4 w0 = *(const float4*)&attn_w[d * CC + c0];
            float4 w1 = *(const float4*)&attn_w[d * CC + c0 + 4];
            h2 p0, p1, p2, p3;
            p0.x = (_Float16)(w0.x * S2); p0.y = (_Float16)(w0.y * S2);
            p1.x = (_Float16)(w0.z * S2); p1.y = (_Float16)(w0.w * S2);
            p2.x = (_Float16)(w1.x * S2); p2.y = (_Float16)(w1.y * S2);
            p3.x = (_Float16)(w1.z * S2); p3.y = (_Float16)(w1.w * S2);
            uint4 o;
            o.x = __builtin_bit_cast(uint32, p0);
            o.y = __builtin_bit_cast(uint32, p1);
            o.z = __builtin_bit_cast(uint32, p2);
            o.w = __builtin_bit_cast(uint32, p3);
            wtbp[idx] = o;
        }
    }
}

// One block per (b, i). Compact valid j's, then tiles of 16 j:
// phase1: threads (c,half) compute delta/alpha/u -> LDS (alpha f16, u f32);
// phase2: scores = alpha(16xK=128) @ wtB(K=128 x 128) via 8 MFMA/wave
//         (B frags preloaded once per block, A frags straight from alpha_h);
// phase3: D-layout lanes (d=lane&15+tile, j=(lane>>4)*4+reg) do masked
//         streaming exp-sum; per-wave j covers all 16 slots so no cross-wave
//         reduction — final shfl_xor(16/32) butterfly + lane<16 store.
__global__ __launch_bounds__(256, 4) void main_kernel(
    const float* __restrict__ pos, const float* __restrict__ nrm,
    const int* __restrict__ rptr, const float* __restrict__ ws,
    float* __restrict__ out)
{
    const float* v    = ws + WS_V;
    const float* asrc = ws + WS_ASRC;
    const float* adst = ws + WS_ADST;
    const float* pwt  = ws + WS_PWT;
    const float* T1   = ws + WS_T1;
    const float* T2   = ws + WS_T2;

    int blk = blockIdx.x;
    int b = blk >> 8, i = blk & 255;
    int tid = threadIdx.x;

    __shared__ float relf[NN * 6];
    __shared__ int   jlist[NN];
    __shared__ int   wcnt[4];
    __shared__ int   cnt_s;
    __shared__ _Float16 alpha_h[16 * 136];  // [slot][c], 272 B rows (16B-aligned)
    __shared__ float    u_lds[16 * 136];    // [slot][c] f32, pitch 136 (bank-spread)

    int rv = rptr[0];
    float r2 = (float)(rv * rv);
    const float* pib = pos + (size_t)(b * NN + i) * 3;
    const float* nib = nrm + (size_t)(b * NN + i) * 3;
    float pix = pib[0], piy = pib[1], piz = pib[2];
    float nix = nib[0], niy = nib[1], niz = nib[2];
    {
        int j = tid;
        const float* pj = pos + (size_t)(b * NN + j) * 3;
        const float* nj = nrm + (size_t)(b * NN + j) * 3;
        float dx = pix - pj[0], dy = piy - pj[1], dz = piz - pj[2];
        float ex = nix - nj[0], ey = niy - nj[1], ez = niz - nj[2];
        float d2 = dx * dx + dy * dy + dz * dz;
        bool valid = (d2 <= r2);
        unsigned long long m = __ballot(valid);
        int w = tid >> 6, lane = tid & 63;
        if (lane == 0) wcnt[w] = __popcll(m);
        __syncthreads();
        int off = 0;
        for (int w2 = 0; w2 < w; ++w2) off += wcnt[w2];
        if (tid == 0) cnt_s = wcnt[0] + wcnt[1] + wcnt[2] + wcnt[3];
        int rank = __popcll(m & ((1ull << lane) - 1ull));
        if (valid) {
            int s = off + rank;
            jlist[s] = j;
            relf[s * 6 + 0] = dx; relf[s * 6 + 1] = dy; relf[s * 6 + 2] = dz;
            relf[s * 6 + 3] = ex; relf[s * 6 + 4] = ey; relf[s * 6 + 5] = ez;
        }
    }
    __syncthreads();
    int cnt = cnt_s;   // >= 1 (self-loop)

    int c    = tid & 127;
    int half = tid >> 7;   // wave-uniform
    int w    = tid >> 6;   // wave id 0..3 -> owns d in [w*32, w*32+32)
    int lane = tid & 63;

    // --- B fragments: 2 d-tiles x 4 K-steps, held in 32 VGPRs for the block ---
    f16x8 bf[2][4];
    {
        const uint4* wtb = (const uint4*)(ws + WS_WTB);
#pragma unroll
        for (int tt = 0; tt < 2; ++tt)
#pragma unroll
            for (int s = 0; s < 4; ++s)
                bf[tt][s] = __builtin_bit_cast(f16x8,
                    wtb[((w * 2 + tt) * 4 + s) * 64 + lane]);
    }
    float T2a = T2[w * 32 + (lane & 15)];
    float T2b = T2[w * 32 + 16 + (lane & 15)];

    float pw[6];
#pragma unroll
    for (int k = 0; k < 6; ++k) pw[k] = pwt[k * CC + c];
    float T1c    = T1[c];
    float adst_c = adst[(b * NN + i) * CC + c];

    float pse0 = 0.f, pov0 = 0.f, pse1 = 0.f, pov1 = 0.f;

    for (int base = 0; base < cnt; base += 16) {
        int tcnt = min(16, cnt - base);
        int myn  = tcnt - half * 8;   // how many of my 8 slots are valid
        // ---- phase 1: alpha (f16) + u (f32) -> LDS ----
#pragma unroll
        for (int q = 0; q < 8; ++q) {
            float aval = 0.f, uval = 0.f;
            if (q < myn) {
                int js = base + half * 8 + q;
                int j  = jlist[js];
                const float2* rp = (const float2*)&relf[js * 6];
                float2 r0 = rp[0], r1 = rp[1], r2f = rp[2];
                float dsum = T1c;
                dsum = fmaf(pw[0], r0.x, dsum);
                dsum = fmaf(pw[1], r0.y, dsum);
                dsum = fmaf(pw[2], r1.x, dsum);
                dsum = fmaf(pw[3], r1.y, dsum);
                dsum = fmaf(pw[4], r2f.x, dsum);
                dsum = fmaf(pw[5], r2f.y, dsum);
                float delta = fmaxf(dsum, 0.f);
                aval = adst_c - asrc[(b * NN + j) * CC + c] + delta;
                uval = v[(b * NN + j) * CC + c] + delta;
            }
            alpha_h[(half * 8 + q) * 136 + c] = (_Float16)aval;
            u_lds[(half * 8 + q) * 136 + c]  = uval;
        }
        __syncthreads();
        // ---- phase 2: scores = alpha @ wtB + T2 via MFMA (8 per wave) ----
        f32x4 acc0 = {T2a, T2a, T2a, T2a};
        f32x4 acc1 = {T2b, T2b, T2b, T2b};
        {
            const _Float16* arow = &alpha_h[(lane & 15) * 136 + ((lane >> 4) << 3)];
#pragma unroll
            for (int s = 0; s < 4; ++s) {
                f16x8 af = *(const f16x8*)(arow + s * 32);
                acc0 = __builtin_amdgcn_mfma_f32_16x16x32_f16(af, bf[0][s], acc0, 0, 0, 0);
                acc1 = __builtin_amdgcn_mfma_f32_16x16x32_f16(af, bf[1][s], acc1, 0, 0, 0);
            }
        }
        // ---- phase 3: masked streaming exp-sum in D layout ----
        {
            int d0 = w * 32 + (lane & 15);
#pragma unroll
            for (int rg = 0; rg < 4; ++rg) {
                int j = ((lane >> 4) << 2) + rg;
                bool jvalid = (j < tcnt);
                float e0 = jvalid ? __expf(fmaxf(acc0[rg], 0.f)) : 0.f;
                float e1 = jvalid ? __expf(fmaxf(acc1[rg], 0.f)) : 0.f;
                pse0 += e0;
                pov0 += e0 * u_lds[j * 136 + d0];
                pse1 += e1;
                pov1 += e1 * u_lds[j * 136 + d0 + 16];
            }
        }
        __syncthreads();
    }

    // ---- reduce the 4 j-groups (lane bits 4,5) and store ----
    pse0 += __shfl_xor(pse0, 16); pse0 += __shfl_xor(pse0, 32);
    pov0 += __shfl_xor(pov0, 16); pov0 += __shfl_xor(pov0, 32);
    pse1 += __shfl_xor(pse1, 16); pse1 += __shfl_xor(pse1, 32);
    pov1 += __shfl_xor(pov1, 16); pov1 += __shfl_xor(pov1, 32);
    if (lane < 16) {
        size_t o = (size_t)(b * NN + i) * CC + w * 32 + lane;
        out[o]      = pov0 / pse0;
        out[o + 16] = pov1 / pse1;
    }
}

extern "C" void kernel_launch(void* const* d_in, const int* in_sizes, int n_in,
                              void* d_out, int out_size, void* d_ws, size_t ws_size,
                              hipStream_t stream) {
    const float* x      = (const float*)d_in[0];
    const float* pos    = (const float*)d_in[1];
    const float* normal = (const float*)d_in[2];
    const float* W_lin  = (const float*)d_in[3];
    const float* W_src  = (const float*)d_in[4];
    const float* W_dst  = (const float*)d_in[5];
    const float* pos_w  = (const float*)d_in[6];
    const float* pos_b  = (const float*)d_in[7];
    const float* pos_g  = (const float*)d_in[8];
    const float* pos_bb = (const float*)d_in[9];
    const float* pos_m  = (const float*)d_in[10];
    const float* pos_v  = (const float*)d_in[11];
    const float* attn_w = (const float*)d_in[12];
    const float* attn_b = (const float*)d_in[13];
    const float* attn_g = (const float*)d_in[14];
    const float* attn_bb= (const float*)d_in[15];
    const float* attn_m = (const float*)d_in[16];
    const float* attn_v = (const float*)d_in[17];
    const int*   rptr   = (const int*)d_in[18];
    float* ws  = (float*)d_ws;
    float* out = (float*)d_out;

    prep_kernel<<<dim3(769), dim3(256), 0, stream>>>(
        x, W_lin, W_src, W_dst, pos_w, pos_b, pos_g, pos_bb, pos_m, pos_v,
        attn_w, attn_b, attn_g, attn_bb, attn_m, attn_v, ws);
    main_kernel<<<dim3(2048), dim3(256), 0, stream>>>(pos, normal, rptr, ws, out);
}

// Round 2
// 113.162 us; speedup vs baseline: 1.1208x; 1.0127x over previous
//
#include <hip/hip_runtime.h>

typedef _Float16 h2 __attribute__((ext_vector_type(2)));
typedef _Float16 f16x8 __attribute__((ext_vector_type(8)));
typedef float f32x4 __attribute__((ext_vector_type(4)));
typedef unsigned int uint32;

#define BB 8
#define NN 256
#define FF 59
#define CC 128
#define EPSV 1e-5f

// ws layout (dword offsets)
#define WS_V     0
#define WS_ASRC  (WS_V + BB*NN*CC)
#define WS_ADST  (WS_ASRC + BB*NN*CC)
#define WS_PWT   (WS_ADST + BB*NN*CC)
#define WS_T1    (WS_PWT + 6*CC)
#define WS_T2    (WS_T1 + CC)
#define WS_WTB   (WS_T2 + CC)   // 32*64 uint4 = 8192 dwords: attn_w folded+packed in MFMA B-fragment order

// blocks 0..767: projections, 8 n-rows each (type = blk>>8: 0=v, 1=a_src, 2=a_dst)
// block  768   : fold BN into pos_w (-> pwt, T1) and attn_w (-> wtB f16 B-fragments, T2)
__global__ __launch_bounds__(256) void prep_kernel(
    const float* __restrict__ x, const float* __restrict__ W_lin,
    const float* __restrict__ W_src, const float* __restrict__ W_dst,
    const float* __restrict__ pos_w, const float* __restrict__ pos_b,
    const float* __restrict__ pos_g, const float* __restrict__ pos_bb,
    const float* __restrict__ pos_m, const float* __restrict__ pos_v,
    const float* __restrict__ attn_w, const float* __restrict__ attn_b,
    const float* __restrict__ attn_g, const float* __restrict__ attn_bb,
    const float* __restrict__ attn_m, const float* __restrict__ attn_v,
    float* __restrict__ ws)
{
    int blk = blockIdx.x;
    int tid = threadIdx.x;
    if (blk < 768) {
        int type = blk >> 8;
        int g    = blk & 255;
        int b    = g >> 5;
        int n0   = (g & 31) * 8;
        const float* W = (type == 0) ? W_lin : (type == 1) ? W_src : W_dst;
        float* outp = ws + ((type == 0) ? WS_V : (type == 1) ? WS_ASRC : WS_ADST);
        // Wl layout [f4][c][4]: lane c reads consecutive float4 -> conflict-free
        // (old [c][60] layout: lane stride 60 dw -> 8-way bank conflict)
        __shared__ float Wl[15 * 128 * 4];
        __shared__ float xs[8 * 60];
        for (int idx = tid; idx < 15 * 128; idx += 256) {
            int f4 = idx >> 7, cc = idx & 127;
            const float* wr = W + cc * FF + f4 * 4;
            float4 wv;
            wv.x = wr[0];
            wv.y = wr[1];
            wv.z = wr[2];
            wv.w = (f4 < 14) ? wr[3] : 0.f;   // f=59 pad
            *(float4*)&Wl[idx * 4] = wv;
        }
        const float* xrow = x + (size_t)(b * NN + n0) * FF;
        for (int idx = tid; idx < 8 * 60; idx += 256) {
            int r = idx / 60, f = idx - r * 60;
            xs[idx] = (f < FF) ? xrow[r * FF + f] : 0.f;
        }
        __syncthreads();
        int c = tid & 127, h = tid >> 7;
        float acc[4];
#pragma unroll
        for (int q = 0; q < 4; ++q) acc[q] = 0.f;
#pragma unroll 3
        for (int f4 = 0; f4 < 15; ++f4) {
            float4 wq = *(const float4*)&Wl[(f4 * 128 + c) * 4];
#pragma unroll
            for (int q = 0; q < 4; ++q) {
                float4 xq = *(const float4*)&xs[(h * 4 + q) * 60 + f4 * 4];
                acc[q] = fmaf(wq.x, xq.x, acc[q]);
                acc[q] = fmaf(wq.y, xq.y, acc[q]);
                acc[q] = fmaf(wq.z, xq.z, acc[q]);
                acc[q] = fmaf(wq.w, xq.w, acc[q]);
            }
        }
#pragma unroll
        for (int q = 0; q < 4; ++q) {
            int n = n0 + h * 4 + q;
            outp[(b * NN + n) * CC + c] = acc[q];
        }
    } else {
        __shared__ float S2s[CC];
        if (tid < CC) {
            int c = tid;
            float S1 = rsqrtf(pos_v[c] + EPSV) * pos_g[c];
            ws[WS_T1 + c] = (pos_b[c] - pos_m[c]) * S1 + pos_bb[c];
#pragma unroll
            for (int k = 0; k < 6; ++k) ws[WS_PWT + k * CC + c] = pos_w[c * 6 + k] * S1;
            float S2 = rsqrtf(attn_v[c] + EPSV) * attn_g[c];
            S2s[c] = S2;
            ws[WS_T2 + c] = (attn_b[c] - attn_m[c]) * S2 + attn_bb[c];
        }
        __syncthreads();
        // Build wtB: f16 B-fragments for mfma_f32_16x16x32_f16.
        // Fragment entry (ts = t*4+s, lane l, elem e):
        //   value = attn_w[d][c]*S2[d],  d = t*16 + (l&15),  c = s*32 + (l>>4)*8 + e
        uint4* wtbp = (uint4*)(ws + WS_WTB);
        for (int idx = tid; idx < 32 * 64; idx += 256) {
            int l = idx & 63, ts = idx >> 6;
            int t = ts >> 2, s = ts & 3;
            int d  = t * 16 + (l & 15);
            int c0 = s * 32 + ((l >> 4) << 3);
            float S2 = S2s[d];
            float4 w0 = *(const float4*)&attn_w[d * CC + c0];
            float4 w1 = *(const float4*)&attn_w[d * CC + c0 + 4];
            h2 p0, p1, p2, p3;
            p0.x = (_Float16)(w0.x * S2); p0.y = (_Float16)(w0.y * S2);
            p1.x = (_Float16)(w0.z * S2); p1.y = (_Float16)(w0.w * S2);
            p2.x = (_Float16)(w1.x * S2); p2.y = (_Float16)(w1.y * S2);
            p3.x = (_Float16)(w1.z * S2); p3.y = (_Float16)(w1.w * S2);
            uint4 o;
            o.x = __builtin_bit_cast(uint32, p0);
            o.y = __builtin_bit_cast(uint32, p1);
            o.z = __builtin_bit_cast(uint32, p2);
            o.w = __builtin_bit_cast(uint32, p3);
            wtbp[idx] = o;
        }
    }
}

// One block per (b, i). Prolog loads (B-frags, pw, T1, T2, adst) hoisted above
// the j-scan so L2 latency hides under scan VALU. Compact valid j's, then
// tiles of 16 j with balanced interleaved slots (s = 2q+half):
// phase1: alpha f16 + u f32 -> LDS (guarded: no zero-fill, stale rows are
//         masked in phase3 by branch, not multiply);
// phase2: scores = alpha(16x128) @ wtB via 8 MFMA/wave;
// phase3: D-layout (d=lane&15+tile, j=(lane>>4)*4+rg) branch-masked exp-sum;
// final shfl_xor(16/32) butterfly + lane<16 store. 4 barriers typical.
__global__ __launch_bounds__(256, 4) void main_kernel(
    const float* __restrict__ pos, const float* __restrict__ nrm,
    const int* __restrict__ rptr, const float* __restrict__ ws,
    float* __restrict__ out)
{
    const float* v    = ws + WS_V;
    const float* asrc = ws + WS_ASRC;
    const float* adst = ws + WS_ADST;
    const float* pwt  = ws + WS_PWT;
    const float* T1   = ws + WS_T1;
    const float* T2   = ws + WS_T2;

    int blk = blockIdx.x;
    int b = blk >> 8, i = blk & 255;
    int tid = threadIdx.x;

    __shared__ float relf[NN * 6];
    __shared__ int   jlist[NN];
    __shared__ int   wcnt[4];
    __shared__ int   cnt_s;
    __shared__ _Float16 alpha_h[16 * 136];  // [slot][c], 272 B rows (16B-aligned)
    __shared__ float    u_lds[16 * 136];    // [slot][c] f32, pitch 136 (bank-spread)

    int c    = tid & 127;
    int half = tid >> 7;   // wave-uniform
    int w    = tid >> 6;   // wave id 0..3 -> owns d in [w*32, w*32+32)
    int lane = tid & 63;

    // ---- hoisted prolog: independent of the scan, latency overlaps it ----
    f16x8 bf[2][4];
    {
        const uint4* wtb = (const uint4*)(ws + WS_WTB);
#pragma unroll
        for (int tt = 0; tt < 2; ++tt)
#pragma unroll
            for (int s = 0; s < 4; ++s)
                bf[tt][s] = __builtin_bit_cast(f16x8,
                    wtb[((w * 2 + tt) * 4 + s) * 64 + lane]);
    }
    float T2a = T2[w * 32 + (lane & 15)];
    float T2b = T2[w * 32 + 16 + (lane & 15)];
    float pw[6];
#pragma unroll
    for (int k = 0; k < 6; ++k) pw[k] = pwt[k * CC + c];
    float T1c    = T1[c];
    float adst_c = adst[(b * NN + i) * CC + c];

    int rv = rptr[0];
    float r2 = (float)(rv * rv);
    const float* pib = pos + (size_t)(b * NN + i) * 3;
    const float* nib = nrm + (size_t)(b * NN + i) * 3;
    float pix = pib[0], piy = pib[1], piz = pib[2];
    float nix = nib[0], niy = nib[1], niz = nib[2];
    {
        int j = tid;
        const float* pj = pos + (size_t)(b * NN + j) * 3;
        const float* nj = nrm + (size_t)(b * NN + j) * 3;
        float dx = pix - pj[0], dy = piy - pj[1], dz = piz - pj[2];
        float ex = nix - nj[0], ey = niy - nj[1], ez = niz - nj[2];
        float d2 = dx * dx + dy * dy + dz * dz;
        bool valid = (d2 <= r2);
        unsigned long long m = __ballot(valid);
        if (lane == 0) wcnt[w] = __popcll(m);
        __syncthreads();
        int off = 0;
        for (int w2 = 0; w2 < w; ++w2) off += wcnt[w2];
        if (tid == 0) cnt_s = wcnt[0] + wcnt[1] + wcnt[2] + wcnt[3];
        int rank = __popcll(m & ((1ull << lane) - 1ull));
        if (valid) {
            int s = off + rank;
            jlist[s] = j;
            relf[s * 6 + 0] = dx; relf[s * 6 + 1] = dy; relf[s * 6 + 2] = dz;
            relf[s * 6 + 3] = ex; relf[s * 6 + 4] = ey; relf[s * 6 + 5] = ez;
        }
    }
    __syncthreads();
    int cnt = cnt_s;   // >= 1 (self-loop)

    float pse0 = 0.f, pov0 = 0.f, pse1 = 0.f, pov1 = 0.f;

    for (int base = 0; base < cnt; base += 16) {
        if (base) __syncthreads();   // protect alpha_h/u_lds reuse (multi-tile only)
        int tcnt = min(16, cnt - base);
        // ---- phase 1: alpha (f16) + u (f32) -> LDS, interleaved slots ----
#pragma unroll
        for (int q = 0; q < 8; ++q) {
            int s = 2 * q + half;   // balanced split between halves
            if (s < tcnt) {
                int js = base + s;
                int j  = jlist[js];
                const float2* rp = (const float2*)&relf[js * 6];
                float2 r0 = rp[0], r1 = rp[1], r2f = rp[2];
                float dsum = T1c;
                dsum = fmaf(pw[0], r0.x, dsum);
                dsum = fmaf(pw[1], r0.y, dsum);
                dsum = fmaf(pw[2], r1.x, dsum);
                dsum = fmaf(pw[3], r1.y, dsum);
                dsum = fmaf(pw[4], r2f.x, dsum);
                dsum = fmaf(pw[5], r2f.y, dsum);
                float delta = fmaxf(dsum, 0.f);
                alpha_h[s * 136 + c] = (_Float16)(adst_c - asrc[(b * NN + j) * CC + c] + delta);
                u_lds[s * 136 + c]   = v[(b * NN + j) * CC + c] + delta;
            }
        }
        __syncthreads();
        // ---- phase 2: scores = alpha @ wtB + T2 via MFMA (8 per wave) ----
        f32x4 acc0 = {T2a, T2a, T2a, T2a};
        f32x4 acc1 = {T2b, T2b, T2b, T2b};
        {
            const _Float16* arow = &alpha_h[(lane & 15) * 136 + ((lane >> 4) << 3)];
#pragma unroll
            for (int s = 0; s < 4; ++s) {
                f16x8 af = *(const f16x8*)(arow + s * 32);
                acc0 = __builtin_amdgcn_mfma_f32_16x16x32_f16(af, bf[0][s], acc0, 0, 0, 0);
                acc1 = __builtin_amdgcn_mfma_f32_16x16x32_f16(af, bf[1][s], acc1, 0, 0, 0);
            }
        }
        // ---- phase 3: branch-masked streaming exp-sum in D layout ----
        {
            int d0 = w * 32 + (lane & 15);
#pragma unroll
            for (int rg = 0; rg < 4; ++rg) {
                int j = ((lane >> 4) << 2) + rg;
                if (j < tcnt) {   // branch, not x0 multiply: stale u_lds rows can't leak
                    float e0 = __expf(fmaxf(acc0[rg], 0.f));
                    float e1 = __expf(fmaxf(acc1[rg], 0.f));
                    pse0 += e0;
                    pov0 += e0 * u_lds[j * 136 + d0];
                    pse1 += e1;
                    pov1 += e1 * u_lds[j * 136 + d0 + 16];
                }
            }
        }
    }

    // ---- reduce the 4 j-groups (lane bits 4,5) and store ----
    pse0 += __shfl_xor(pse0, 16); pse0 += __shfl_xor(pse0, 32);
    pov0 += __shfl_xor(pov0, 16); pov0 += __shfl_xor(pov0, 32);
    pse1 += __shfl_xor(pse1, 16); pse1 += __shfl_xor(pse1, 32);
    pov1 += __shfl_xor(pov1, 16); pov1 += __shfl_xor(pov1, 32);
    if (lane < 16) {
        size_t o = (size_t)(b * NN + i) * CC + w * 32 + lane;
        out[o]      = pov0 / pse0;
        out[o + 16] = pov1 / pse1;
    }
}

extern "C" void kernel_launch(void* const* d_in, const int* in_sizes, int n_in,
                              void* d_out, int out_size, void* d_ws, size_t ws_size,
                              hipStream_t stream) {
    const float* x      = (const float*)d_in[0];
    const float* pos    = (const float*)d_in[1];
    const float* normal = (const float*)d_in[2];
    const float* W_lin  = (const float*)d_in[3];
    const float* W_src  = (const float*)d_in[4];
    const float* W_dst  = (const float*)d_in[5];
    const float* pos_w  = (const float*)d_in[6];
    const float* pos_b  = (const float*)d_in[7];
    const float* pos_g  = (const float*)d_in[8];
    const float* pos_bb = (const float*)d_in[9];
    const float* pos_m  = (const float*)d_in[10];
    const float* pos_v  = (const float*)d_in[11];
    const float* attn_w = (const float*)d_in[12];
    const float* attn_b = (const float*)d_in[13];
    const float* attn_g = (const float*)d_in[14];
    const float* attn_bb= (const float*)d_in[15];
    const float* attn_m = (const float*)d_in[16];
    const float* attn_v = (const float*)d_in[17];
    const int*   rptr   = (const int*)d_in[18];
    float* ws  = (float*)d_ws;
    float* out = (float*)d_out;

    prep_kernel<<<dim3(769), dim3(256), 0, stream>>>(
        x, W_lin, W_src, W_dst, pos_w, pos_b, pos_g, pos_bb, pos_m, pos_v,
        attn_w, attn_b, attn_g, attn_bb, attn_m, attn_v, ws);
    main_kernel<<<dim3(2048), dim3(256), 0, stream>>>(pos, normal, rptr, ws, out);
}

// Round 4
// 109.864 us; speedup vs baseline: 1.1545x; 1.0300x over previous
//
#include <hip/hip_runtime.h>

typedef _Float16 h2 __attribute__((ext_vector_type(2)));
typedef _Float16 f16x8 __attribute__((ext_vector_type(8)));
typedef float f32x4 __attribute__((ext_vector_type(4)));
typedef unsigned int uint32;

#define BB 8
#define NN 256
#define FF 59
#define CC 128
#define EPSV 1e-5f

// ws layout (dword offsets)
#define WS_V     0
#define WS_ASRC  (WS_V + BB*NN*CC)
#define WS_ADST  (WS_ASRC + BB*NN*CC)
#define WS_PWT   (WS_ADST + BB*NN*CC)
#define WS_T1    (WS_PWT + 6*CC)
#define WS_T2    (WS_T1 + CC)
#define WS_WTB   (WS_T2 + CC)   // 32*64 uint4 = 8192 dwords: attn_w folded+packed in MFMA B-fragment order

// blocks 0..767: projections, 8 n-rows each (type = blk>>8: 0=v, 1=a_src, 2=a_dst)
// block  768   : fold BN into pos_w (-> pwt, T1) and attn_w (-> wtB f16 B-fragments, T2)
__global__ __launch_bounds__(256) void prep_kernel(
    const float* __restrict__ x, const float* __restrict__ W_lin,
    const float* __restrict__ W_src, const float* __restrict__ W_dst,
    const float* __restrict__ pos_w, const float* __restrict__ pos_b,
    const float* __restrict__ pos_g, const float* __restrict__ pos_bb,
    const float* __restrict__ pos_m, const float* __restrict__ pos_v,
    const float* __restrict__ attn_w, const float* __restrict__ attn_b,
    const float* __restrict__ attn_g, const float* __restrict__ attn_bb,
    const float* __restrict__ attn_m, const float* __restrict__ attn_v,
    float* __restrict__ ws)
{
    int blk = blockIdx.x;
    int tid = threadIdx.x;
    if (blk < 768) {
        int type = blk >> 8;
        int g    = blk & 255;
        int b    = g >> 5;
        int n0   = (g & 31) * 8;
        const float* W = (type == 0) ? W_lin : (type == 1) ? W_src : W_dst;
        float* outp = ws + ((type == 0) ? WS_V : (type == 1) ? WS_ASRC : WS_ADST);
        // Linear staging: thread t copies W[t] -> fully coalesced global reads,
        // stride-1 LDS writes. Compute reads Wl[c*59+f]: lane stride 59 (odd)
        // spreads all 32 banks (~2-way = free).
        __shared__ float Wl[CC * FF];   // 7552 floats
        __shared__ float xs[8 * 60];
        for (int idx = tid; idx < CC * FF; idx += 256) Wl[idx] = W[idx];
        const float* xrow = x + (size_t)(b * NN + n0) * FF;
        for (int idx = tid; idx < 8 * 60; idx += 256) {
            int r = idx / 60, f = idx - r * 60;
            xs[idx] = (f < FF) ? xrow[r * FF + f] : 0.f;
        }
        __syncthreads();
        int c = tid & 127, h = tid >> 7;
        const float* wrow = &Wl[c * FF];
        float acc[4];
#pragma unroll
        for (int q = 0; q < 4; ++q) acc[q] = 0.f;
#pragma unroll 2
        for (int f4 = 0; f4 < 14; ++f4) {
            float w0 = wrow[f4 * 4 + 0];
            float w1 = wrow[f4 * 4 + 1];
            float w2 = wrow[f4 * 4 + 2];
            float w3 = wrow[f4 * 4 + 3];
#pragma unroll
            for (int q = 0; q < 4; ++q) {
                float4 xq = *(const float4*)&xs[(h * 4 + q) * 60 + f4 * 4];
                acc[q] = fmaf(w0, xq.x, acc[q]);
                acc[q] = fmaf(w1, xq.y, acc[q]);
                acc[q] = fmaf(w2, xq.z, acc[q]);
                acc[q] = fmaf(w3, xq.w, acc[q]);
            }
        }
        {   // tail f = 56..58
            float w0 = wrow[56], w1 = wrow[57], w2 = wrow[58];
#pragma unroll
            for (int q = 0; q < 4; ++q) {
                const float* xr = &xs[(h * 4 + q) * 60];
                acc[q] = fmaf(w0, xr[56], acc[q]);
                acc[q] = fmaf(w1, xr[57], acc[q]);
                acc[q] = fmaf(w2, xr[58], acc[q]);
            }
        }
#pragma unroll
        for (int q = 0; q < 4; ++q) {
            int n = n0 + h * 4 + q;
            outp[(b * NN + n) * CC + c] = acc[q];
        }
    } else {
        __shared__ float S2s[CC];
        if (tid < CC) {
            int c = tid;
            float S1 = rsqrtf(pos_v[c] + EPSV) * pos_g[c];
            ws[WS_T1 + c] = (pos_b[c] - pos_m[c]) * S1 + pos_bb[c];
#pragma unroll
            for (int k = 0; k < 6; ++k) ws[WS_PWT + k * CC + c] = pos_w[c * 6 + k] * S1;
            float S2 = rsqrtf(attn_v[c] + EPSV) * attn_g[c];
            S2s[c] = S2;
            ws[WS_T2 + c] = (attn_b[c] - attn_m[c]) * S2 + attn_bb[c];
        }
        __syncthreads();
        // Build wtB: f16 B-fragments for mfma_f32_16x16x32_f16.
        // Fragment entry (ts = t*4+s, lane l, elem e):
        //   value = attn_w[d][c]*S2[d],  d = t*16 + (l&15),  c = s*32 + (l>>4)*8 + e
        uint4* wtbp = (uint4*)(ws + WS_WTB);
        for (int idx = tid; idx < 32 * 64; idx += 256) {
            int l = idx & 63, ts = idx >> 6;
            int t = ts >> 2, s = ts & 3;
            int d  = t * 16 + (l & 15);
            int c0 = s * 32 + ((l >> 4) << 3);
            float S2 = S2s[d];
            float4 w0 = *(const float4*)&attn_w[d * CC + c0];
            float4 w1 = *(const float4*)&attn_w[d * CC + c0 + 4];
            h2 p0, p1, p2, p3;
            p0.x = (_Float16)(w0.x * S2); p0.y = (_Float16)(w0.y * S2);
            p1.x = (_Float16)(w0.z * S2); p1.y = (_Float16)(w0.w * S2);
            p2.x = (_Float16)(w1.x * S2); p2.y = (_Float16)(w1.y * S2);
            p3.x = (_Float16)(w1.z * S2); p3.y = (_Float16)(w1.w * S2);
            uint4 o;
            o.x = __builtin_bit_cast(uint32, p0);
            o.y = __builtin_bit_cast(uint32, p1);
            o.z = __builtin_bit_cast(uint32, p2);
            o.w = __builtin_bit_cast(uint32, p3);
            wtbp[idx] = o;
        }
    }
}

// One block per (b, i-pair): 1024 blocks == exactly the 4-blocks/CU residency
// -> single co-resident generation (no sequential rounds), and the invariant
// prolog (B-frags, pw, T1, T2) is loaded once per block, not once per i.
// Per i: compact valid j's, then tiles of 16 j:
// phase1: alpha f16 + u f32 -> LDS (guarded; stale rows branch-masked later);
// phase2: scores = alpha(16x128) @ wtB via 8 MFMA/wave;
// phase3: D-layout (d=lane&15+tile, j=(lane>>4)*4+rg) branch-masked exp-sum;
// shfl_xor(16/32) butterfly + lane<16 store.
// Cross-i safety: a wave reaches i1's scan only after i0's last phase1-end
// barrier; i1's jlist/relf/cnt_s writes occur only after i1's first scan
// barrier, which can't be passed until all waves finish i0's phase 3.
__global__ __launch_bounds__(256, 4) void main_kernel(
    const float* __restrict__ pos, const float* __restrict__ nrm,
    const int* __restrict__ rptr, const float* __restrict__ ws,
    float* __restrict__ out)
{
    const float* v    = ws + WS_V;
    const float* asrc = ws + WS_ASRC;
    const float* adst = ws + WS_ADST;
    const float* pwt  = ws + WS_PWT;
    const float* T1   = ws + WS_T1;
    const float* T2   = ws + WS_T2;

    int blk = blockIdx.x;
    int b  = blk >> 7;
    int i0 = (blk & 127) * 2;
    int tid = threadIdx.x;

    __shared__ float relf[NN * 6];
    __shared__ int   jlist[NN];
    __shared__ int   wcnt[4];
    __shared__ int   cnt_s;
    __shared__ _Float16 alpha_h[16 * 136];  // [slot][c], 272 B rows (16B-aligned for b128)
    __shared__ float    u_lds[16 * 132];    // [slot][c] f32, pitch 132: phase3 reads 2-way (free)

    int c    = tid & 127;
    int half = tid >> 7;   // wave-uniform
    int w    = tid >> 6;   // wave id 0..3 -> owns d in [w*32, w*32+32)
    int lane = tid & 63;

    // ---- hoisted invariant prolog: shared by both i's ----
    f16x8 bf[2][4];
    {
        const uint4* wtb = (const uint4*)(ws + WS_WTB);
#pragma unroll
        for (int tt = 0; tt < 2; ++tt)
#pragma unroll
            for (int s = 0; s < 4; ++s)
                bf[tt][s] = __builtin_bit_cast(f16x8,
                    wtb[((w * 2 + tt) * 4 + s) * 64 + lane]);
    }
    float T2a = T2[w * 32 + (lane & 15)];
    float T2b = T2[w * 32 + 16 + (lane & 15)];
    float pw[6];
#pragma unroll
    for (int k = 0; k < 6; ++k) pw[k] = pwt[k * CC + c];
    float T1c = T1[c];
    int rv = rptr[0];
    float r2 = (float)(rv * rv);

    for (int ii = 0; ii < 2; ++ii) {
        int i = i0 + ii;
        float adst_c = adst[(b * NN + i) * CC + c];
        const float* pib = pos + (size_t)(b * NN + i) * 3;
        const float* nib = nrm + (size_t)(b * NN + i) * 3;
        float pix = pib[0], piy = pib[1], piz = pib[2];
        float nix = nib[0], niy = nib[1], niz = nib[2];
        {
            int j = tid;
            const float* pj = pos + (size_t)(b * NN + j) * 3;
            const float* nj = nrm + (size_t)(b * NN + j) * 3;
            float dx = pix - pj[0], dy = piy - pj[1], dz = piz - pj[2];
            float ex = nix - nj[0], ey = niy - nj[1], ez = niz - nj[2];
            float d2 = dx * dx + dy * dy + dz * dz;
            bool valid = (d2 <= r2);
            unsigned long long m = __ballot(valid);
            if (lane == 0) wcnt[w] = __popcll(m);
            __syncthreads();
            int off = 0;
            for (int w2 = 0; w2 < w; ++w2) off += wcnt[w2];
            if (tid == 0) cnt_s = wcnt[0] + wcnt[1] + wcnt[2] + wcnt[3];
            int rank = __popcll(m & ((1ull << lane) - 1ull));
            if (valid) {
                int s = off + rank;
                jlist[s] = j;
                relf[s * 6 + 0] = dx; relf[s * 6 + 1] = dy; relf[s * 6 + 2] = dz;
                relf[s * 6 + 3] = ex; relf[s * 6 + 4] = ey; relf[s * 6 + 5] = ez;
            }
        }
        __syncthreads();
        int cnt = cnt_s;   // >= 1 (self-loop)

        float pse0 = 0.f, pov0 = 0.f, pse1 = 0.f, pov1 = 0.f;

        for (int base = 0; base < cnt; base += 16) {
            if (base) __syncthreads();   // alpha_h/u_lds reuse (multi-tile only)
            int tcnt = min(16, cnt - base);
            // ---- phase 1: alpha (f16) + u (f32) -> LDS, interleaved slots ----
#pragma unroll
            for (int q = 0; q < 8; ++q) {
                int s = 2 * q + half;   // balanced split between halves
                if (s < tcnt) {
                    int js = base + s;
                    int j  = jlist[js];
                    const float2* rp = (const float2*)&relf[js * 6];
                    float2 r0 = rp[0], r1 = rp[1], r2f = rp[2];
                    float dsum = T1c;
                    dsum = fmaf(pw[0], r0.x, dsum);
                    dsum = fmaf(pw[1], r0.y, dsum);
                    dsum = fmaf(pw[2], r1.x, dsum);
                    dsum = fmaf(pw[3], r1.y, dsum);
                    dsum = fmaf(pw[4], r2f.x, dsum);
                    dsum = fmaf(pw[5], r2f.y, dsum);
                    float delta = fmaxf(dsum, 0.f);
                    alpha_h[s * 136 + c] = (_Float16)(adst_c - asrc[(b * NN + j) * CC + c] + delta);
                    u_lds[s * 132 + c]   = v[(b * NN + j) * CC + c] + delta;
                }
            }
            __syncthreads();
            // ---- phase 2: scores = alpha @ wtB + T2 via MFMA (8 per wave) ----
            f32x4 acc0 = {T2a, T2a, T2a, T2a};
            f32x4 acc1 = {T2b, T2b, T2b, T2b};
            {
                const _Float16* arow = &alpha_h[(lane & 15) * 136 + ((lane >> 4) << 3)];
#pragma unroll
                for (int s = 0; s < 4; ++s) {
                    f16x8 af = *(const f16x8*)(arow + s * 32);
                    acc0 = __builtin_amdgcn_mfma_f32_16x16x32_f16(af, bf[0][s], acc0, 0, 0, 0);
                    acc1 = __builtin_amdgcn_mfma_f32_16x16x32_f16(af, bf[1][s], acc1, 0, 0, 0);
                }
            }
            // ---- phase 3: branch-masked streaming exp-sum in D layout ----
            {
                int d0 = w * 32 + (lane & 15);
#pragma unroll
                for (int rg = 0; rg < 4; ++rg) {
                    int j = ((lane >> 4) << 2) + rg;
                    if (j < tcnt) {   // branch, not x0 multiply: stale rows can't leak
                        float e0 = __expf(fmaxf(acc0[rg], 0.f));
                        float e1 = __expf(fmaxf(acc1[rg], 0.f));
                        pse0 += e0;
                        pov0 += e0 * u_lds[j * 132 + d0];
                        pse1 += e1;
                        pov1 += e1 * u_lds[j * 132 + d0 + 16];
                    }
                }
            }
        }

        // ---- reduce the 4 j-groups (lane bits 4,5) and store ----
        pse0 += __shfl_xor(pse0, 16); pse0 += __shfl_xor(pse0, 32);
        pov0 += __shfl_xor(pov0, 16); pov0 += __shfl_xor(pov0, 32);
        pse1 += __shfl_xor(pse1, 16); pse1 += __shfl_xor(pse1, 32);
        pov1 += __shfl_xor(pov1, 16); pov1 += __shfl_xor(pov1, 32);
        if (lane < 16) {
            size_t o = (size_t)(b * NN + i) * CC + w * 32 + lane;
            out[o]      = pov0 / pse0;
            out[o + 16] = pov1 / pse1;
        }
    }
}

extern "C" void kernel_launch(void* const* d_in, const int* in_sizes, int n_in,
                              void* d_out, int out_size, void* d_ws, size_t ws_size,
                              hipStream_t stream) {
    const float* x      = (const float*)d_in[0];
    const float* pos    = (const float*)d_in[1];
    const float* normal = (const float*)d_in[2];
    const float* W_lin  = (const float*)d_in[3];
    const float* W_src  = (const float*)d_in[4];
    const float* W_dst  = (const float*)d_in[5];
    const float* pos_w  = (const float*)d_in[6];
    const float* pos_b  = (const float*)d_in[7];
    const float* pos_g  = (const float*)d_in[8];
    const float* pos_bb = (const float*)d_in[9];
    const float* pos_m  = (const float*)d_in[10];
    const float* pos_v  = (const float*)d_in[11];
    const float* attn_w = (const float*)d_in[12];
    const float* attn_b = (const float*)d_in[13];
    const float* attn_g = (const float*)d_in[14];
    const float* attn_bb= (const float*)d_in[15];
    const float* attn_m = (const float*)d_in[16];
    const float* attn_v = (const float*)d_in[17];
    const int*   rptr   = (const int*)d_in[18];
    float* ws  = (float*)d_ws;
    float* out = (float*)d_out;

    prep_kernel<<<dim3(769), dim3(256), 0, stream>>>(
        x, W_lin, W_src, W_dst, pos_w, pos_b, pos_g, pos_bb, pos_m, pos_v,
        attn_w, attn_b, attn_g, attn_bb, attn_m, attn_v, ws);
    main_kernel<<<dim3(1024), dim3(256), 0, stream>>>(pos, normal, rptr, ws, out);
}